// Round 2
// baseline (340.894 us; speedup 1.0000x reference)
//
#include <hip/hip_runtime.h>
#include <hip/hip_bf16.h>
#include <stdint.h>

// Shapes fixed by the problem: N=16, C=128, H*W=16384, out_chn=128.
#define NB    16
#define CD    128
#define HW    16384

typedef float  f32x4  __attribute__((ext_vector_type(4)));
typedef short  bf16x8 __attribute__((ext_vector_type(8)));

// fp32 -> bf16 round-to-nearest-even
__device__ __forceinline__ unsigned f2bf(float f) {
    unsigned u = __float_as_uint(f);
    u += 0x7FFFu + ((u >> 16) & 1u);
    return u >> 16;
}

// ---------------------------------------------------------------------------
// Kernel 1: G[n] += X_chunk * X_chunk^T  (bf16 MFMA, fp32 atomic accumulate)
// grid (16 n, 64 kchunks of 256), 256 threads -> 1024 blocks (~4/CU, 16 wv/CU).
// LDS tile 128x132 bf16 (pad -> 2-way conflicts, free per m136).
// ---------------------------------------------------------------------------
__global__ __launch_bounds__(256) void gram_kernel(const float* __restrict__ x,
                                                   float* __restrict__ G) {
    const int n  = blockIdx.x;
    const int kc = blockIdx.y;
    const int t    = threadIdx.x;
    const int wv   = t >> 6;
    const int lane = t & 63;
    const int q    = lane >> 4;   // 0..3
    const int r16  = lane & 15;

    __shared__ __align__(16) unsigned short Xl[CD * 132];

    f32x4 acc[4][4];
#pragma unroll
    for (int i = 0; i < 4; ++i)
#pragma unroll
        for (int j = 0; j < 4; ++j) acc[i][j] = (f32x4)0.0f;

    const int rt0 = 4 * (wv >> 1);   // row-tile base (of 8 16-wide tiles)
    const int ct0 = 4 * (wv & 1);    // col-tile base

    const float* xb = x + (size_t)n * CD * HW;

    for (int sub = 0; sub < 2; ++sub) {
        const int kbase = kc * 256 + sub * 128;
        // stage 128 rows x 128 k fp32 -> bf16 LDS (coalesced float4 reads)
#pragma unroll
        for (int i = 0; i < 16; ++i) {
            int f  = i * 256 + t;
            int c  = f >> 5;
            int l4 = (f & 31) * 4;
            float4 v = *(const float4*)(xb + (size_t)c * HW + kbase + l4);
            uint2 pk;
            pk.x = f2bf(v.x) | (f2bf(v.y) << 16);
            pk.y = f2bf(v.z) | (f2bf(v.w) << 16);
            *(uint2*)(&Xl[c * 132 + l4]) = pk;
        }
        __syncthreads();

#pragma unroll
        for (int ks = 0; ks < 4; ++ks) {
            const int k0 = ks * 32 + q * 8;
            bf16x8 af[4], bfr[4];
#pragma unroll
            for (int i = 0; i < 4; ++i) {
                const unsigned short* pa = &Xl[(16 * (rt0 + i) + r16) * 132 + k0];
                union { bf16x8 v; uint2 u[2]; } ua;
                ua.u[0] = *(const uint2*)pa;
                ua.u[1] = *(const uint2*)(pa + 4);
                af[i] = ua.v;
                const unsigned short* pb = &Xl[(16 * (ct0 + i) + r16) * 132 + k0];
                union { bf16x8 v; uint2 u[2]; } ub;
                ub.u[0] = *(const uint2*)pb;
                ub.u[1] = *(const uint2*)(pb + 4);
                bfr[i] = ub.v;
            }
#pragma unroll
            for (int i = 0; i < 4; ++i)
#pragma unroll
                for (int j = 0; j < 4; ++j)
                    acc[i][j] = __builtin_amdgcn_mfma_f32_16x16x32_bf16(
                        af[i], bfr[j], acc[i][j], 0, 0, 0);
        }
        __syncthreads();
    }

    float* Gn = G + (size_t)n * CD * CD;
#pragma unroll
    for (int i = 0; i < 4; ++i)
#pragma unroll
        for (int j = 0; j < 4; ++j)
#pragma unroll
            for (int rr = 0; rr < 4; ++rr) {
                // C/D layout (m89): col = lane&15, row = (lane>>4)*4 + reg
                int row = 16 * (rt0 + i) + q * 4 + rr;
                int col = 16 * (ct0 + j) + r16;
                atomicAdd(&Gn[row * CD + col], acc[i][j][rr]);
            }
}

// ---------------------------------------------------------------------------
// Kernel 2: per-row softmax stats (max, 1/sum(exp)). One wave per row.
// ---------------------------------------------------------------------------
__global__ __launch_bounds__(256) void rowstats_kernel(const float* __restrict__ G,
                                                       float* __restrict__ mx,
                                                       float* __restrict__ rs) {
    const int row  = blockIdx.x * 4 + (threadIdx.x >> 6);
    const int lane = threadIdx.x & 63;
    const float* g = G + (size_t)row * CD;
    float g0 = g[lane];
    float g1 = g[lane + 64];
    float m = fmaxf(g0, g1);
#pragma unroll
    for (int off = 32; off > 0; off >>= 1) m = fmaxf(m, __shfl_xor(m, off));
    float s = __expf(g0 - m) + __expf(g1 - m);
#pragma unroll
    for (int off = 32; off > 0; off >>= 1) s += __shfl_xor(s, off);
    if (lane == 0) {
        mx[row] = m;
        rs[row] = 1.0f / s;
    }
}

// ---------------------------------------------------------------------------
// Kernel 3: M[n] = conv_w @ softmax(G[n])  -> bf16.
// ---------------------------------------------------------------------------
__global__ __launch_bounds__(256) void mmat_kernel(const float* __restrict__ G,
                                                   const float* __restrict__ mx,
                                                   const float* __restrict__ rs,
                                                   const float* __restrict__ cw,
                                                   unsigned short* __restrict__ Mbf) {
    const int n  = blockIdx.x;
    const int bo = blockIdx.y;
    const int t  = threadIdx.x;
    __shared__ __align__(16) float Wl[CD * CD];   // 64 KiB exactly

    const float* Gn  = G  + (size_t)n * CD * CD;
    const float* mxn = mx + n * CD;
    const float* rsn = rs + n * CD;

#pragma unroll 4
    for (int i = 0; i < 64; ++i) {
        int e = i * 256 + t;
        int c = e >> 7;
        int d = e & 127;
        Wl[c * CD + d] = __expf(Gn[c * CD + d] - mxn[c]) * rsn[c];
    }
    __syncthreads();

    const int o  = bo * 16 + (t >> 4);
    const int d0 = (t & 15) * 8;
    float a0 = 0, a1 = 0, a2 = 0, a3 = 0, a4 = 0, a5 = 0, a6 = 0, a7 = 0;
    const float* cwo = cw + (size_t)o * CD;
#pragma unroll 4
    for (int c = 0; c < CD; ++c) {
        float cv = cwo[c];
        float4 w0 = *(const float4*)&Wl[c * CD + d0];
        float4 w1 = *(const float4*)&Wl[c * CD + d0 + 4];
        a0 += cv * w0.x; a1 += cv * w0.y; a2 += cv * w0.z; a3 += cv * w0.w;
        a4 += cv * w1.x; a5 += cv * w1.y; a6 += cv * w1.z; a7 += cv * w1.w;
    }
    uint4 pk;
    pk.x = f2bf(a0) | (f2bf(a1) << 16);
    pk.y = f2bf(a2) | (f2bf(a3) << 16);
    pk.z = f2bf(a4) | (f2bf(a5) << 16);
    pk.w = f2bf(a6) | (f2bf(a7) << 16);
    *(uint4*)&Mbf[((size_t)n * CD + o) * CD + d0] = pk;
}

// ---------------------------------------------------------------------------
// Kernel 4: out[n] = M[n] @ X[n] + bias, computed as D[l][o] = sum_c X[c][l]M[o][c].
// A-operand = X^T from LDS (XOR-swizzled, pad-free, b128 reads); B-operand = M
// straight from global (contiguous, L2-hot). Epilogue: float4 stores (l-contig).
// Staging: 4x4 in-register transpose -> 16 ds_write_b64, ~4-way conflicts.
// Swizzle: phys(l, d) = l*128 + (d ^ (8*((l>>2)&7))), preserves 8-aligned runs.
// ---------------------------------------------------------------------------
__global__ __launch_bounds__(256) void out_kernel(const float* __restrict__ x,
                                                  const unsigned short* __restrict__ Mbf,
                                                  const float* __restrict__ bias,
                                                  float* __restrict__ out) {
    const int lb = blockIdx.x;      // 128 chunks of 128 pixels
    const int n  = blockIdx.y;
    const int l0 = lb * 128;
    const int t    = threadIdx.x;
    const int wv   = t >> 6;
    const int lane = t & 63;
    const int q    = lane >> 4;
    const int r16  = lane & 15;

    __shared__ __align__(16) unsigned short Xt[128 * 128];  // 32 KiB, swizzled
    __shared__ float bl[CD];

    const int lt0 = 4 * (wv >> 1);   // l-tile base (D rows)
    const int ot0 = 4 * (wv & 1);    // o-tile base (D cols)

    if (t < CD) bl[t] = bias[t];

    // Stage X[n][d][l0..l0+127] fp32 -> bf16, transposed via 4x4 register tiles
    const float* xb = x + (size_t)n * CD * HW + l0;
    const int lt = t & 31;
    const int dg = t >> 5;
#pragma unroll
    for (int i = 0; i < 4; ++i) {
        const int d0 = i * 32 + dg * 4;
        const float* bp = xb + (size_t)d0 * HW + 4 * lt;
        float4 v0 = *(const float4*)(bp);
        float4 v1 = *(const float4*)(bp + HW);
        float4 v2 = *(const float4*)(bp + 2 * HW);
        float4 v3 = *(const float4*)(bp + 3 * HW);
        float r0[4] = {v0.x, v0.y, v0.z, v0.w};
        float r1[4] = {v1.x, v1.y, v1.z, v1.w};
        float r2[4] = {v2.x, v2.y, v2.z, v2.w};
        float r3[4] = {v3.x, v3.y, v3.z, v3.w};
        const int dph = d0 ^ (8 * (lt & 7));
#pragma unroll
        for (int j = 0; j < 4; ++j) {
            uint2 pk;
            pk.x = f2bf(r0[j]) | (f2bf(r1[j]) << 16);
            pk.y = f2bf(r2[j]) | (f2bf(r3[j]) << 16);
            *(uint2*)&Xt[(4 * lt + j) * 128 + dph] = pk;
        }
    }
    __syncthreads();

    f32x4 acc[4][4];
#pragma unroll
    for (int i = 0; i < 4; ++i)
#pragma unroll
        for (int j = 0; j < 4; ++j) acc[i][j] = (f32x4)0.0f;

    const unsigned short* Mn = Mbf + (size_t)n * CD * CD;
#pragma unroll
    for (int ks = 0; ks < 4; ++ks) {
        const int k0 = ks * 32 + q * 8;
        // B-frags: B[k=c][col=o] = M[o][c] -> contiguous 16B from global
        bf16x8 bfr[4];
#pragma unroll
        for (int j = 0; j < 4; ++j) {
            const int o = 16 * (ot0 + j) + r16;
            union { bf16x8 v; uint4 u; } ub;
            ub.u = *(const uint4*)&Mn[o * CD + k0];
            bfr[j] = ub.v;
        }
        // A-frags: A[m=l][k=c] = X[c][l] from swizzled LDS, b128
        bf16x8 af[4];
#pragma unroll
        for (int i = 0; i < 4; ++i) {
            const int l = 16 * (lt0 + i) + r16;
            const int doff = k0 ^ (8 * ((l >> 2) & 7));
            union { bf16x8 v; uint4 u; } ua;
            ua.u = *(const uint4*)&Xt[l * 128 + doff];
            af[i] = ua.v;
        }
#pragma unroll
        for (int i = 0; i < 4; ++i)
#pragma unroll
            for (int j = 0; j < 4; ++j)
                acc[i][j] = __builtin_amdgcn_mfma_f32_16x16x32_bf16(
                    af[i], bfr[j], acc[i][j], 0, 0, 0);
    }

    // D[row=l][col=o]: lane holds col o=r16-within-tile, rows q*4+rr -> l-contig
    float* ob = out + (size_t)n * CD * HW + l0;
#pragma unroll
    for (int i = 0; i < 4; ++i)
#pragma unroll
        for (int j = 0; j < 4; ++j) {
            const int o = 16 * (ot0 + j) + r16;
            const int l = 16 * (lt0 + i) + q * 4;
            const float b = bl[o];
            float4 st;
            st.x = acc[i][j][0] + b;
            st.y = acc[i][j][1] + b;
            st.z = acc[i][j][2] + b;
            st.w = acc[i][j][3] + b;
            *(float4*)(ob + (size_t)o * HW + l) = st;
        }
}

// ---------------------------------------------------------------------------
extern "C" void kernel_launch(void* const* d_in, const int* in_sizes, int n_in,
                              void* d_out, int out_size, void* d_ws, size_t ws_size,
                              hipStream_t stream) {
    const float* x  = (const float*)d_in[0];   // (16,128,128,128) fp32
    const float* cw = (const float*)d_in[1];   // (128,128) fp32
    const float* cb = (const float*)d_in[2];   // (128,) fp32
    float* out = (float*)d_out;                // (16,128,128,128) fp32

    char* ws = (char*)d_ws;
    float*          G   = (float*)(ws);                      // 1 MiB
    float*          mxp = (float*)(ws + (1u << 20));         // 8 KiB
    float*          rsp = (float*)(ws + (1u << 20) + 8192);  // 8 KiB
    unsigned short* Mbf = (unsigned short*)(ws + (1u << 20) + 16384); // 512 KiB

    hipMemsetAsync(G, 0, (size_t)NB * CD * CD * sizeof(float), stream);

    gram_kernel    <<<dim3(NB, 64), 256, 0, stream>>>(x, G);
    rowstats_kernel<<<dim3(512),    256, 0, stream>>>(G, mxp, rsp);
    mmat_kernel    <<<dim3(NB, 8),  256, 0, stream>>>(G, mxp, rsp, cw, Mbf);
    out_kernel     <<<dim3(128, NB), 256, 0, stream>>>(x, Mbf, cb, out);
}

// Round 3
// 303.259 us; speedup vs baseline: 1.1241x; 1.1241x over previous
//
#include <hip/hip_runtime.h>
#include <hip/hip_bf16.h>
#include <stdint.h>

// Shapes fixed by the problem: N=16, C=128, H*W=16384, out_chn=128.
#define NB    16
#define CD    128
#define HW    16384
#define KSPLIT 32   // gram K-splits per batch; each block covers HW/KSPLIT = 512

typedef float  f32x4  __attribute__((ext_vector_type(4)));
typedef short  bf16x8 __attribute__((ext_vector_type(8)));

// fp32 -> bf16 round-to-nearest-even
__device__ __forceinline__ unsigned f2bf(float f) {
    unsigned u = __float_as_uint(f);
    u += 0x7FFFu + ((u >> 16) & 1u);
    return u >> 16;
}

// ---------------------------------------------------------------------------
// Kernel 1: partial Gram tiles. P[kc][n] = X[:, kc*512:(kc+1)*512] @ (same)^T
// grid (16 n, 32 kc), 256 threads. Plain fp32 stores — NO atomics (round-2
// post-mortem: memory-side atomic RMW was 64 MB of HBM churn, 107 us).
// LDS tile 128x132 bf16 (pad -> 2-way conflicts, free per m136; R2 measured 0).
// ---------------------------------------------------------------------------
__global__ __launch_bounds__(256) void gram_kernel(const float* __restrict__ x,
                                                   float* __restrict__ P) {
    const int n  = blockIdx.x;
    const int kc = blockIdx.y;
    const int t    = threadIdx.x;
    const int wv   = t >> 6;
    const int lane = t & 63;
    const int q    = lane >> 4;   // 0..3
    const int r16  = lane & 15;

    __shared__ __align__(16) unsigned short Xl[CD * 132];

    f32x4 acc[4][4];
#pragma unroll
    for (int i = 0; i < 4; ++i)
#pragma unroll
        for (int j = 0; j < 4; ++j) acc[i][j] = (f32x4)0.0f;

    const int rt0 = 4 * (wv >> 1);   // row-tile base (of 8 16-wide tiles)
    const int ct0 = 4 * (wv & 1);    // col-tile base

    const float* xb = x + (size_t)n * CD * HW;

    for (int sub = 0; sub < 4; ++sub) {
        const int kbase = kc * 512 + sub * 128;
        // stage 128 rows x 128 k fp32 -> bf16 LDS (coalesced float4 reads)
#pragma unroll
        for (int i = 0; i < 16; ++i) {
            int f  = i * 256 + t;
            int c  = f >> 5;
            int l4 = (f & 31) * 4;
            float4 v = *(const float4*)(xb + (size_t)c * HW + kbase + l4);
            uint2 pk;
            pk.x = f2bf(v.x) | (f2bf(v.y) << 16);
            pk.y = f2bf(v.z) | (f2bf(v.w) << 16);
            *(uint2*)(&Xl[c * 132 + l4]) = pk;
        }
        __syncthreads();

#pragma unroll
        for (int ks = 0; ks < 4; ++ks) {
            const int k0 = ks * 32 + q * 8;
            bf16x8 af[4], bfr[4];
#pragma unroll
            for (int i = 0; i < 4; ++i) {
                const unsigned short* pa = &Xl[(16 * (rt0 + i) + r16) * 132 + k0];
                union { bf16x8 v; uint2 u[2]; } ua;
                ua.u[0] = *(const uint2*)pa;
                ua.u[1] = *(const uint2*)(pa + 4);
                af[i] = ua.v;
                const unsigned short* pb = &Xl[(16 * (ct0 + i) + r16) * 132 + k0];
                union { bf16x8 v; uint2 u[2]; } ub;
                ub.u[0] = *(const uint2*)pb;
                ub.u[1] = *(const uint2*)(pb + 4);
                bfr[i] = ub.v;
            }
#pragma unroll
            for (int i = 0; i < 4; ++i)
#pragma unroll
                for (int j = 0; j < 4; ++j)
                    acc[i][j] = __builtin_amdgcn_mfma_f32_16x16x32_bf16(
                        af[i], bfr[j], acc[i][j], 0, 0, 0);
        }
        __syncthreads();
    }

    float* Pn = P + ((size_t)kc * NB + n) * CD * CD;
#pragma unroll
    for (int i = 0; i < 4; ++i)
#pragma unroll
        for (int j = 0; j < 4; ++j)
#pragma unroll
            for (int rr = 0; rr < 4; ++rr) {
                // C/D layout (m89): col = lane&15, row = (lane>>4)*4 + reg
                int row = 16 * (rt0 + i) + q * 4 + rr;
                int col = 16 * (ct0 + j) + r16;
                Pn[row * CD + col] = acc[i][j][rr];
            }
}

// ---------------------------------------------------------------------------
// Kernel 2: reduce 32 partials per G-row + softmax stats (max, 1/sum(exp)).
// One wave per row; 2048 rows -> 512 blocks x 256 threads.
// ---------------------------------------------------------------------------
__global__ __launch_bounds__(256) void reduce_kernel(const float* __restrict__ P,
                                                     float* __restrict__ G,
                                                     float* __restrict__ mx,
                                                     float* __restrict__ rs) {
    const int R    = blockIdx.x * 4 + (threadIdx.x >> 6); // 0..2047
    const int lane = threadIdx.x & 63;
    const int n    = R >> 7;
    const int row  = R & 127;

    const float* p = P + (size_t)n * CD * CD + (size_t)row * CD;
    float s0 = 0.0f, s1 = 0.0f;
#pragma unroll
    for (int kc = 0; kc < KSPLIT; ++kc) {
        const float* pk = p + (size_t)kc * NB * CD * CD;
        s0 += pk[lane];
        s1 += pk[lane + 64];
    }
    float m = fmaxf(s0, s1);
#pragma unroll
    for (int off = 32; off > 0; off >>= 1) m = fmaxf(m, __shfl_xor(m, off));
    float e = __expf(s0 - m) + __expf(s1 - m);
#pragma unroll
    for (int off = 32; off > 0; off >>= 1) e += __shfl_xor(e, off);

    float* g = G + (size_t)n * CD * CD + (size_t)row * CD;
    g[lane]      = s0;
    g[lane + 64] = s1;
    if (lane == 0) {
        mx[R] = m;
        rs[R] = 1.0f / e;
    }
}

// ---------------------------------------------------------------------------
// Kernel 3: M[n] = conv_w @ softmax(G[n])  -> bf16.
// ---------------------------------------------------------------------------
__global__ __launch_bounds__(256) void mmat_kernel(const float* __restrict__ G,
                                                   const float* __restrict__ mx,
                                                   const float* __restrict__ rs,
                                                   const float* __restrict__ cw,
                                                   unsigned short* __restrict__ Mbf) {
    const int n  = blockIdx.x;
    const int bo = blockIdx.y;
    const int t  = threadIdx.x;
    __shared__ __align__(16) float Wl[CD * CD];   // 64 KiB exactly

    const float* Gn  = G  + (size_t)n * CD * CD;
    const float* mxn = mx + n * CD;
    const float* rsn = rs + n * CD;

#pragma unroll 4
    for (int i = 0; i < 64; ++i) {
        int e = i * 256 + t;
        int c = e >> 7;
        int d = e & 127;
        Wl[c * CD + d] = __expf(Gn[c * CD + d] - mxn[c]) * rsn[c];
    }
    __syncthreads();

    const int o  = bo * 16 + (t >> 4);
    const int d0 = (t & 15) * 8;
    float a0 = 0, a1 = 0, a2 = 0, a3 = 0, a4 = 0, a5 = 0, a6 = 0, a7 = 0;
    const float* cwo = cw + (size_t)o * CD;
#pragma unroll 4
    for (int c = 0; c < CD; ++c) {
        float cv = cwo[c];
        float4 w0 = *(const float4*)&Wl[c * CD + d0];
        float4 w1 = *(const float4*)&Wl[c * CD + d0 + 4];
        a0 += cv * w0.x; a1 += cv * w0.y; a2 += cv * w0.z; a3 += cv * w0.w;
        a4 += cv * w1.x; a5 += cv * w1.y; a6 += cv * w1.z; a7 += cv * w1.w;
    }
    uint4 pk;
    pk.x = f2bf(a0) | (f2bf(a1) << 16);
    pk.y = f2bf(a2) | (f2bf(a3) << 16);
    pk.z = f2bf(a4) | (f2bf(a5) << 16);
    pk.w = f2bf(a6) | (f2bf(a7) << 16);
    *(uint4*)&Mbf[((size_t)n * CD + o) * CD + d0] = pk;
}

// ---------------------------------------------------------------------------
// Kernel 4: out[n] = M[n] @ X[n] + bias, computed as D[l][o] = sum_c X[c][l]M[o][c].
// A-operand = X^T from LDS (XOR-swizzled, pad-free, b128 reads); B-operand = M
// straight from global (contiguous, L2-hot). Epilogue: float4 stores (l-contig).
// Swizzle: phys(l, d) = l*128 + (d ^ (8*((l>>2)&7))), preserves 8-aligned runs.
// ---------------------------------------------------------------------------
__global__ __launch_bounds__(256) void out_kernel(const float* __restrict__ x,
                                                  const unsigned short* __restrict__ Mbf,
                                                  const float* __restrict__ bias,
                                                  float* __restrict__ out) {
    const int lb = blockIdx.x;      // 128 chunks of 128 pixels
    const int n  = blockIdx.y;
    const int l0 = lb * 128;
    const int t    = threadIdx.x;
    const int wv   = t >> 6;
    const int lane = t & 63;
    const int q    = lane >> 4;
    const int r16  = lane & 15;

    __shared__ __align__(16) unsigned short Xt[128 * 128];  // 32 KiB, swizzled
    __shared__ float bl[CD];

    const int lt0 = 4 * (wv >> 1);   // l-tile base (D rows)
    const int ot0 = 4 * (wv & 1);    // o-tile base (D cols)

    if (t < CD) bl[t] = bias[t];

    // Stage X[n][d][l0..l0+127] fp32 -> bf16, transposed via 4x4 register tiles
    const float* xb = x + (size_t)n * CD * HW + l0;
    const int lt = t & 31;
    const int dg = t >> 5;
#pragma unroll
    for (int i = 0; i < 4; ++i) {
        const int d0 = i * 32 + dg * 4;
        const float* bp = xb + (size_t)d0 * HW + 4 * lt;
        float4 v0 = *(const float4*)(bp);
        float4 v1 = *(const float4*)(bp + HW);
        float4 v2 = *(const float4*)(bp + 2 * HW);
        float4 v3 = *(const float4*)(bp + 3 * HW);
        float r0[4] = {v0.x, v0.y, v0.z, v0.w};
        float r1[4] = {v1.x, v1.y, v1.z, v1.w};
        float r2[4] = {v2.x, v2.y, v2.z, v2.w};
        float r3[4] = {v3.x, v3.y, v3.z, v3.w};
        const int dph = d0 ^ (8 * (lt & 7));
#pragma unroll
        for (int j = 0; j < 4; ++j) {
            uint2 pk;
            pk.x = f2bf(r0[j]) | (f2bf(r1[j]) << 16);
            pk.y = f2bf(r2[j]) | (f2bf(r3[j]) << 16);
            *(uint2*)&Xt[(4 * lt + j) * 128 + dph] = pk;
        }
    }
    __syncthreads();

    f32x4 acc[4][4];
#pragma unroll
    for (int i = 0; i < 4; ++i)
#pragma unroll
        for (int j = 0; j < 4; ++j) acc[i][j] = (f32x4)0.0f;

    const unsigned short* Mn = Mbf + (size_t)n * CD * CD;
#pragma unroll
    for (int ks = 0; ks < 4; ++ks) {
        const int k0 = ks * 32 + q * 8;
        // B-frags: B[k=c][col=o] = M[o][c] -> contiguous 16B from global
        bf16x8 bfr[4];
#pragma unroll
        for (int j = 0; j < 4; ++j) {
            const int o = 16 * (ot0 + j) + r16;
            union { bf16x8 v; uint4 u; } ub;
            ub.u = *(const uint4*)&Mn[o * CD + k0];
            bfr[j] = ub.v;
        }
        // A-frags: A[m=l][k=c] = X[c][l] from swizzled LDS, b128
        bf16x8 af[4];
#pragma unroll
        for (int i = 0; i < 4; ++i) {
            const int l = 16 * (lt0 + i) + r16;
            const int doff = k0 ^ (8 * ((l >> 2) & 7));
            union { bf16x8 v; uint4 u; } ua;
            ua.u = *(const uint4*)&Xt[l * 128 + doff];
            af[i] = ua.v;
        }
#pragma unroll
        for (int i = 0; i < 4; ++i)
#pragma unroll
            for (int j = 0; j < 4; ++j)
                acc[i][j] = __builtin_amdgcn_mfma_f32_16x16x32_bf16(
                    af[i], bfr[j], acc[i][j], 0, 0, 0);
    }

    // D[row=l][col=o]: lane holds col o=r16-within-tile, rows q*4+rr -> l-contig
    float* ob = out + (size_t)n * CD * HW + l0;
#pragma unroll
    for (int i = 0; i < 4; ++i)
#pragma unroll
        for (int j = 0; j < 4; ++j) {
            const int o = 16 * (ot0 + j) + r16;
            const int l = 16 * (lt0 + i) + q * 4;
            const float b = bl[o];
            float4 st;
            st.x = acc[i][j][0] + b;
            st.y = acc[i][j][1] + b;
            st.z = acc[i][j][2] + b;
            st.w = acc[i][j][3] + b;
            *(float4*)(ob + (size_t)o * HW + l) = st;
        }
}

// ---------------------------------------------------------------------------
extern "C" void kernel_launch(void* const* d_in, const int* in_sizes, int n_in,
                              void* d_out, int out_size, void* d_ws, size_t ws_size,
                              hipStream_t stream) {
    const float* x  = (const float*)d_in[0];   // (16,128,128,128) fp32
    const float* cw = (const float*)d_in[1];   // (128,128) fp32
    const float* cb = (const float*)d_in[2];   // (128,) fp32
    float* out = (float*)d_out;                // (16,128,128,128) fp32

    char* ws = (char*)d_ws;
    float*          P   = (float*)(ws);                       // 32 MiB partials
    float*          G   = (float*)(ws + (32u << 20));         // 1 MiB
    float*          mxp = (float*)(ws + (33u << 20));         // 8 KiB
    float*          rsp = (float*)(ws + (33u << 20) + 8192);  // 8 KiB
    unsigned short* Mbf = (unsigned short*)(ws + (33u << 20) + 16384); // 512 KiB

    gram_kernel   <<<dim3(NB, KSPLIT), 256, 0, stream>>>(x, P);
    reduce_kernel <<<dim3(512),        256, 0, stream>>>(P, G, mxp, rsp);
    mmat_kernel   <<<dim3(NB, 8),      256, 0, stream>>>(G, mxp, rsp, cw, Mbf);
    out_kernel    <<<dim3(128, NB),    256, 0, stream>>>(x, Mbf, cb, out);
}